// Round 13
// baseline (190.508 us; speedup 1.0000x reference)
//
#include <hip/hip_runtime.h>

#define WIN 442
#define HOP 4
#define NBINS 221
#define LC 128          // windows per chunk = scan segment (measured optimum)
#define SPAN 960        // staged samples per chunk (>= 4*127+446 = 954)
#define GSZ 32          // chunks per compose group

// ================= compile-time twiddle tables (f64-accurate trig) =================
constexpr double kPI = 3.14159265358979323846264338327950288;

constexpr double tsin_poly(double r) {
    double t = r, s = r;
    for (int n = 1; n <= 9; ++n) { t *= -(r * r) / ((2.0 * n) * (2.0 * n + 1.0)); s += t; }
    return s;
}
constexpr double tcos_poly(double r) {
    double t = 1.0, c = 1.0;
    for (int n = 1; n <= 9; ++n) { t *= -(r * r) / ((2.0 * n - 1.0) * (2.0 * n)); c += t; }
    return c;
}
struct SC { double s, c; };
constexpr SC tsincos(double a) {            // a in [0, 2pi)
    int q = (int)(a / (kPI / 2) + 0.5);
    double r = a - q * (kPI / 2);
    double sr = tsin_poly(r), cr = tcos_poly(r);
    switch (q & 3) {
        case 0: return {sr, cr};
        case 1: return {cr, -sr};
        case 2: return {-sr, -cr};
        default: return {-cr, sr};
    }
}
struct TabF { float c[WIN]; float s[WIN]; };     // omega^t = (cos, -sin), f32
constexpr TabF make_tabf() {
    TabF t{};
    for (int i = 0; i < WIN; ++i) {
        SC sc = tsincos(2.0 * kPI * (double)i / 442.0);
        t.c[i] = (float)sc.c; t.s[i] = (float)(-sc.s);
    }
    return t;
}
struct TabR { double c4[NBINS], s4[NBINS], c8[NBINS], s8[NBINS]; };  // cos/sin of 4θ, 8θ (f64)
constexpr TabR make_tabr() {
    TabR t{};
    for (int k = 0; k < NBINS; ++k) {
        SC a = tsincos(2.0 * kPI * (double)((4 * k) % WIN) / 442.0);
        t.c4[k] = a.c; t.s4[k] = a.s;
        SC b = tsincos(2.0 * kPI * (double)((8 * k) % WIN) / 442.0);
        t.c8[k] = b.c; t.s8[k] = b.s;
    }
    return t;
}
__constant__ TabF cTabF = make_tabf();
__constant__ TabR cTabR = make_tabr();

// 64-bit xor-shuffle (reg-pair; compiler folds the pack/unpack)
static __device__ __forceinline__ unsigned long long shflx64(unsigned long long v, int off) {
    unsigned int lo = (unsigned int)v, hi = (unsigned int)(v >> 32);
    lo = __shfl_xor(lo, off, 64);
    hi = __shfl_xor(hi, off, 64);
    return ((unsigned long long)hi << 32) | lo;
}

// ---------------- Kernel B: sliding DFT + argmax + chunk-map + last-block group compose ----
// Slide/argmax identical to R12 (R8-exact, bit-identical a_arr). Map tail now ILP-2:
// bins tid and tid+128 chained interleaved; bin recovered as round(mF/100) (R8-validated).
// After M0 write, each block bumps cnt[group]; the last arriver composes the group's
// GSZ chunk-maps (LDS-staged, reusing the block's smem) into M1[group] -> no sm1 kernel.
__global__ __launch_bounds__(128) void k_slide(
    const float* __restrict__ x, int n, int n_win, int n_chunks,
    int* __restrict__ a_arr, unsigned short* __restrict__ M0,
    int* __restrict__ M1, int* __restrict__ cnt) {
    __shared__ __align__(16) unsigned char smem[15360];
    __shared__ int composeFlag;
    float* Xs  = reinterpret_cast<float*>(smem);                       // SPAN floats
    float* Ds_ = reinterpret_cast<float*>(smem + SPAN * 4);            // LC*4 floats
    unsigned long long* cand =
        reinterpret_cast<unsigned long long*>(smem + SPAN * 4 + LC * 16);  // LC*9 u64

    const int tid = threadIdx.x;
    const int lane = tid & 63;
    const int wc = tid >> 6;                 // bin half (2 waves)
    const int chunk = blockIdx.x;
    const int s0 = chunk * (LC * HOP);

    for (int i = tid; i < SPAN; i += 128) {
        int g = s0 + i;
        Xs[i] = (g < n) ? x[g] : 0.0f;
    }
    __syncthreads();
    for (int r = tid; r < LC * 4; r += 128) Ds_[r] = Xs[r + WIN] - Xs[r];
    __syncthreads();

    const int wlen = min(LC, n_win - chunk * LC);

    const int k0 = lane + 128 * wc, k1 = k0 + 64;
    const bool a0 = (k0 < NBINS), a1 = (k1 < NBINS);
    const int kk0 = a0 ? k0 : 0, kk1 = a1 ? k1 : 0;
    const unsigned int lo0 = 255u - (unsigned)k0, lo1 = 255u - (unsigned)k1;

    float ec0[8], es0[8], ec1[8], es1[8];
    {
        int t0 = 0, t1 = 0;
#pragma unroll
        for (int m = 1; m < 8; ++m) {
            t0 += kk0; if (t0 >= WIN) t0 -= WIN;
            ec0[m] = cTabF.c[t0]; es0[m] = cTabF.s[t0];
            t1 += kk1; if (t1 >= WIN) t1 -= WIN;
            ec1[m] = cTabF.c[t1]; es1[m] = cTabF.s[t1];
        }
    }
    double C40 = a0 ? cTabR.c4[kk0] : 0.0, S40 = a0 ? cTabR.s4[kk0] : 0.0;
    double C41 = a1 ? cTabR.c4[kk1] : 0.0, S41 = a1 ? cTabR.s4[kk1] : 0.0;
    const double C80 = cTabR.c8[kk0], S80 = cTabR.s8[kk0];
    const double C81 = cTabR.c8[kk1], S81 = cTabR.s8[kk1];

    double S0r, S0i, S1r, S1i;
    {   // ---- init: f64 Horner, descending 8-sample f32 groups ----
        float xa = Xs[440], xb = Xs[441];
        S0r = (double)fmaf(xb, ec0[1], xa);
        S0i = (double)(xb * es0[1]);
        S1r = (double)fmaf(xb, ec1[1], xa);
        S1i = (double)(xb * es1[1]);
        const float4* Xq = (const float4*)Xs;
#pragma unroll 1
        for (int t = 54; t >= 0; --t) {
            float4 va = Xq[2 * t], vb = Xq[2 * t + 1];
            float Dr0 = va.x;
            Dr0 = fmaf(va.y, ec0[1], Dr0); Dr0 = fmaf(va.z, ec0[2], Dr0);
            Dr0 = fmaf(va.w, ec0[3], Dr0); Dr0 = fmaf(vb.x, ec0[4], Dr0);
            Dr0 = fmaf(vb.y, ec0[5], Dr0); Dr0 = fmaf(vb.z, ec0[6], Dr0);
            Dr0 = fmaf(vb.w, ec0[7], Dr0);
            float Di0 = va.y * es0[1];
            Di0 = fmaf(va.z, es0[2], Di0); Di0 = fmaf(va.w, es0[3], Di0);
            Di0 = fmaf(vb.x, es0[4], Di0); Di0 = fmaf(vb.y, es0[5], Di0);
            Di0 = fmaf(vb.z, es0[6], Di0); Di0 = fmaf(vb.w, es0[7], Di0);
            double nr = fma(S0r, C80, fma(S0i, S80, (double)Dr0));
            double ni = fma(S0i, C80, fma(S0r, -S80, (double)Di0));
            S0r = nr; S0i = ni;
            float Dr1 = va.x;
            Dr1 = fmaf(va.y, ec1[1], Dr1); Dr1 = fmaf(va.z, ec1[2], Dr1);
            Dr1 = fmaf(va.w, ec1[3], Dr1); Dr1 = fmaf(vb.x, ec1[4], Dr1);
            Dr1 = fmaf(vb.y, ec1[5], Dr1); Dr1 = fmaf(vb.z, ec1[6], Dr1);
            Dr1 = fmaf(vb.w, ec1[7], Dr1);
            float Di1 = va.y * es1[1];
            Di1 = fmaf(va.z, es1[2], Di1); Di1 = fmaf(va.w, es1[3], Di1);
            Di1 = fmaf(vb.x, es1[4], Di1); Di1 = fmaf(vb.y, es1[5], Di1);
            Di1 = fmaf(vb.z, es1[6], Di1); Di1 = fmaf(vb.w, es1[7], Di1);
            nr = fma(S1r, C81, fma(S1i, S81, (double)Dr1));
            ni = fma(S1i, C81, fma(S1r, -S81, (double)Di1));
            S1r = nr; S1i = ni;
        }
    }
    if (!a0) { S0r = 0.0; S0i = 0.0; }
    if (!a1) { S1r = 0.0; S1i = 0.0; }

    const float4* Dq = (const float4*)Ds_;
    for (int b = 0; b < 16; ++b) {           // 16 batches x 8 windows
        unsigned long long key[8];
#pragma unroll
        for (int u = 0; u < 8; ++u) {
            if (b | u) {
                float4 d = Dq[b * 8 + u - 1];
                float Dr0 = fmaf(d.w, ec0[3], fmaf(d.z, ec0[2], fmaf(d.y, ec0[1], d.x)));
                float Di0 = fmaf(d.w, es0[3], fmaf(d.z, es0[2], d.y * es0[1]));
                double nr = S0r + (double)Dr0;
                double ni = S0i + (double)Di0;
                S0r = fma(nr, C40, -(ni * S40));
                S0i = fma(nr, S40, ni * C40);
                float Dr1 = fmaf(d.w, ec1[3], fmaf(d.z, ec1[2], fmaf(d.y, ec1[1], d.x)));
                float Di1 = fmaf(d.w, es1[3], fmaf(d.z, es1[2], d.y * es1[1]));
                nr = S1r + (double)Dr1;
                ni = S1i + (double)Di1;
                S1r = fma(nr, C41, -(ni * S41));
                S1i = fma(nr, S41, ni * C41);
            }
            float m0 = (float)(fabs(S0r) + fabs(S0i));
            float m1 = (float)(fabs(S1r) + fabs(S1i));
            unsigned long long key0 = ((unsigned long long)__float_as_uint(m0) << 32) | lo0;
            unsigned long long key1 = ((unsigned long long)__float_as_uint(m1) << 32) | lo1;
            key[u] = (key1 > key0) ? key1 : key0;
        }
        // ---- 8 interleaved u64 butterflies, stages 32,16,8,4 ----
#pragma unroll
        for (int s = 0; s < 4; ++s) {
            const int off = 32 >> s;
#pragma unroll
            for (int u = 0; u < 8; ++u) {
                unsigned long long o = shflx64(key[u], off);
                if (o > key[u]) key[u] = o;
            }
        }
        if (lane < 4) {
#pragma unroll
            for (int u = 0; u < 8; ++u) cand[(b * 8 + u) * 9 + wc * 4 + lane] = key[u];
        }
    }
    __syncthreads();
    // ---- merge 8 candidates per window; stash t-values in dead Ds_ region ----
    float* tfl = Ds_;
    if (tid < wlen) {
        unsigned long long best = cand[tid * 9];
#pragma unroll
        for (int i = 1; i < 8; ++i) {
            unsigned long long c = cand[tid * 9 + i];
            if (c > best) best = c;
        }
        int a = 255 - (int)(best & 255u);
        a_arr[chunk * LC + tid] = a;
        tfl[tid] = 100.0f * (float)a;
    }
    __syncthreads();
    // ---- fused chunk map, ILP-2: bins tid and tid+128 chained interleaved ----
    {
        int b0 = tid, b1 = tid + 128;
        bool act1 = (b1 < NBINS);
        float mF0 = 100.0f * (float)b0;
        float mF1 = act1 ? 100.0f * (float)b1 : 100.0f;
        int rel0 = -1, rel1 = -1;
        for (int i = 0; i < wlen; ++i) {
            float t = tfl[i];
            if (fabsf(mF0 - t) > mF0 * 0.0594f) { mF0 = t; rel0 = i; }
            if (fabsf(mF1 - t) > mF1 * 0.0594f) { mF1 = t; rel1 = i; }
        }
        int bin0 = __float2int_rn(mF0 * 0.01f);
        M0[chunk * NBINS + b0] = (unsigned short)(((rel0 + 1) << 8) | bin0);
        if (act1) {
            int bin1 = __float2int_rn(mF1 * 0.01f);
            M0[chunk * NBINS + b1] = (unsigned short)(((rel1 + 1) << 8) | bin1);
        }
    }
    // ---- last block of each GSZ-group composes the group's maps -> M1 ----
    __syncthreads();
    const int grp = chunk / GSZ;
    const int c0 = grp * GSZ;
    const int cn = min(GSZ, n_chunks - c0);
    if (tid == 0) {
        __threadfence();                           // release own M0 writes
        int old = atomicAdd(&cnt[grp], 1);
        composeFlag = (old == cn - 1);
    }
    __syncthreads();
    if (composeFlag) {
        __threadfence();                           // acquire others' M0 writes
        unsigned short* smap = reinterpret_cast<unsigned short*>(smem);  // 14.1 KB reuse
        for (int i = tid; i < cn * NBINS; i += 128) smap[i] = M0[c0 * NBINS + i];
        __syncthreads();
        int b0 = tid, b1 = tid + 128;
        bool act1 = (b1 < NBINS);
        int bin0 = b0, bin1 = act1 ? b1 : 0;
        int rw0 = -1, rw1 = -1;
        for (int i = 0; i < cn; ++i) {
            unsigned short mp0 = smap[i * NBINS + bin0];
            if (mp0 >> 8) { rw0 = (c0 + i) * LC + (int)(mp0 >> 8) - 1; bin0 = mp0 & 255; }
            unsigned short mp1 = smap[i * NBINS + bin1];
            if (mp1 >> 8) { rw1 = (c0 + i) * LC + (int)(mp1 >> 8) - 1; bin1 = mp1 & 255; }
        }
        M1[grp * NBINS + b0] = ((rw0 + 1) << 8) | bin0;
        if (act1) M1[grp * NBINS + b1] = ((rw1 + 1) << 8) | bin1;
    }
}

// ---------------- Kernel F: emit (fused entry-chain) ----------------
// Thread 0 chains the entry state: <=61 M1 steps + <=31 M0 steps through L2
// (overlapped across 1953 co-resident blocks; no LDS staging -> no occupancy hit).
// Then thread-per-window rescan from LDS, exactly as R12.
__global__ __launch_bounds__(128) void k_emit(const int* __restrict__ a_arr,
    const unsigned short* __restrict__ M0, const int* __restrict__ M1, int n_win,
    float* __restrict__ flags, float* __restrict__ freqs, float* __restrict__ durs,
    float* __restrict__ out_final) {
    __shared__ float tf[LC];
    __shared__ float sh[2];
    int j = blockIdx.x;
    int wbeg = j * LC;
    int cnt = n_win - wbeg; if (cnt > LC) cnt = LC;
    if (cnt <= 0) return;
    for (int i = threadIdx.x; i < cnt; i += 128) tf[i] = 100.0f * (float)a_arr[wbeg + i];
    if (threadIdx.x == 0) {
        int g = j / GSZ;
        int bin = 0, rw = -1;
        for (int i = 0; i < g; ++i) {                  // cross-group prefix through M1
            int mp = M1[i * NBINS + bin];
            if (mp >> 8) { rw = (mp >> 8) - 1; bin = mp & 255; }
        }
        for (int q = g * GSZ; q < j; ++q) {            // within-group prefix through M0
            unsigned short mp = M0[q * NBINS + bin];
            if (mp >> 8) { rw = q * LC + (int)(mp >> 8) - 1; bin = mp & 255; }
        }
        sh[0] = 100.0f * (float)bin;
        sh[1] = (rw < 0) ? 0.0f : 4.0f * (float)rw;
    }
    __syncthreads();
    int t = threadIdx.x;
    if (t < cnt) {
        float maxF = sh[0];
        float Ftime = sh[1];
        for (int i = 0; i < t; ++i) {
            float tv = tf[i];
            if (fabsf(maxF - tv) > maxF * 0.0594f) {
                maxF = tv; Ftime = 4.0f * (float)(wbeg + i);
            }
        }
        int w = wbeg + t;
        float tv = tf[t];
        float iw = 4.0f * (float)w;
        bool cond = fabsf(maxF - tv) > maxF * 0.0594f;
        flags[w] = cond ? 1.0f : 0.0f;
        freqs[w] = maxF;
        durs[w] = (iw - Ftime) * 1000.0f / 44100.0f;
        if (w == n_win - 1) {                          // fold final-state output here
            float fMax = cond ? tv : maxF;
            float fT   = cond ? iw : Ftime;
            out_final[0] = fMax;
            out_final[1] = (iw - fT) * 1000.0f / 44100.0f;
        }
    }
}

extern "C" void kernel_launch(void* const* d_in, const int* in_sizes, int n_in,
                              void* d_out, int out_size, void* d_ws, size_t ws_size,
                              hipStream_t stream) {
    const float* x = (const float*)d_in[0];
    int n = in_sizes[0];
    int n_win = (n - WIN + HOP - 1) / HOP;
    float* out = (float*)d_out;
    char* ws = (char*)d_ws;

    int n_chunks = (n_win + LC - 1) / LC;             // 1953 @ n=1e6
    int ngrp = (n_chunks + GSZ - 1) / GSZ;            // 62

    // ws layout (~1.92 MB)
    int* a_arr         = (int*)(ws + 0);                     // 1953*128*4 = 999,936 B
    unsigned short* M0 = (unsigned short*)(ws + 1000448);    // 1953*221*2 = 863,226 B
    int* M1            = (int*)(ws + 1864192);               // 62*221*4 = 54,808 B
    int* cnt           = (int*)(ws + 1919232);               // 62*4 B

    hipMemsetAsync(cnt, 0, (size_t)ngrp * 4, stream);
    k_slide<<<dim3(n_chunks), dim3(128), 0, stream>>>(x, n, n_win, n_chunks,
                                                      a_arr, M0, M1, cnt);
    k_emit<<<dim3(n_chunks), dim3(128), 0, stream>>>(a_arr, M0, M1, n_win,
                                                     out, out + (size_t)n_win,
                                                     out + 2 * (size_t)n_win,
                                                     out + 3 * (size_t)n_win);
}

// Round 14
// 158.856 us; speedup vs baseline: 1.1992x; 1.1992x over previous
//
#include <hip/hip_runtime.h>

#define WIN 442
#define HOP 4
#define NBINS 221
#define LC 128          // windows per chunk = scan segment (measured optimum)
#define SPAN 960        // staged samples per chunk (>= 4*127+446 = 954)
#define GSZ 32          // chunks per compose group

// ================= compile-time twiddle tables (f64-accurate trig) =================
constexpr double kPI = 3.14159265358979323846264338327950288;

constexpr double tsin_poly(double r) {
    double t = r, s = r;
    for (int n = 1; n <= 9; ++n) { t *= -(r * r) / ((2.0 * n) * (2.0 * n + 1.0)); s += t; }
    return s;
}
constexpr double tcos_poly(double r) {
    double t = 1.0, c = 1.0;
    for (int n = 1; n <= 9; ++n) { t *= -(r * r) / ((2.0 * n - 1.0) * (2.0 * n)); c += t; }
    return c;
}
struct SC { double s, c; };
constexpr SC tsincos(double a) {            // a in [0, 2pi)
    int q = (int)(a / (kPI / 2) + 0.5);
    double r = a - q * (kPI / 2);
    double sr = tsin_poly(r), cr = tcos_poly(r);
    switch (q & 3) {
        case 0: return {sr, cr};
        case 1: return {cr, -sr};
        case 2: return {-sr, -cr};
        default: return {-cr, sr};
    }
}
struct TabF { float c[WIN]; float s[WIN]; };     // omega^t = (cos, -sin), f32
constexpr TabF make_tabf() {
    TabF t{};
    for (int i = 0; i < WIN; ++i) {
        SC sc = tsincos(2.0 * kPI * (double)i / 442.0);
        t.c[i] = (float)sc.c; t.s[i] = (float)(-sc.s);
    }
    return t;
}
struct TabR { double c4[NBINS], s4[NBINS], c8[NBINS], s8[NBINS]; };  // cos/sin of 4θ, 8θ (f64)
constexpr TabR make_tabr() {
    TabR t{};
    for (int k = 0; k < NBINS; ++k) {
        SC a = tsincos(2.0 * kPI * (double)((4 * k) % WIN) / 442.0);
        t.c4[k] = a.c; t.s4[k] = a.s;
        SC b = tsincos(2.0 * kPI * (double)((8 * k) % WIN) / 442.0);
        t.c8[k] = b.c; t.s8[k] = b.s;
    }
    return t;
}
__constant__ TabF cTabF = make_tabf();
__constant__ TabR cTabR = make_tabr();

// 64-bit xor-shuffle (reg-pair; compiler folds the pack/unpack)
static __device__ __forceinline__ unsigned long long shflx64(unsigned long long v, int off) {
    unsigned int lo = (unsigned int)v, hi = (unsigned int)(v >> 32);
    lo = __shfl_xor(lo, off, 64);
    hi = __shfl_xor(hi, off, 64);
    return ((unsigned long long)hi << 32) | lo;
}

// ---------------- Kernel B: sliding DFT (f64 state) + argmax + fused chunk-map ----------------
// R12-exact slide + argmax (LC=128, 128 threads, 2 waves, 2 bins/lane, 4-stage butterfly,
// cand[LC][9], LDS 15360). Chunk-map tail upgraded to ILP-2: bins tid and tid+128
// chained interleaved in one pass; bin recovered as round(mF/100) (R8-validated).
// No cross-block work here (R13's fused compose regressed -> removed).
__global__ __launch_bounds__(128) void k_slide(
    const float* __restrict__ x, int n, int n_win, int n_chunks,
    int* __restrict__ a_arr, unsigned short* __restrict__ M0) {
    __shared__ __align__(16) float Xs[SPAN];
    __shared__ __align__(16) float Ds_[LC * 4];
    __shared__ unsigned long long cand[LC][9];   // [8] used; pad breaks bank aliasing

    const int tid = threadIdx.x;
    const int lane = tid & 63;
    const int wc = tid >> 6;                 // bin half (2 waves)
    const int chunk = blockIdx.x;
    const int s0 = chunk * (LC * HOP);

    for (int i = tid; i < SPAN; i += 128) {
        int g = s0 + i;
        Xs[i] = (g < n) ? x[g] : 0.0f;
    }
    __syncthreads();
    for (int r = tid; r < LC * 4; r += 128) Ds_[r] = Xs[r + WIN] - Xs[r];
    __syncthreads();

    const int wlen = min(LC, n_win - chunk * LC);

    const int k0 = lane + 128 * wc, k1 = k0 + 64;
    const bool a0 = (k0 < NBINS), a1 = (k1 < NBINS);
    const int kk0 = a0 ? k0 : 0, kk1 = a1 ? k1 : 0;
    const unsigned int lo0 = 255u - (unsigned)k0, lo1 = 255u - (unsigned)k1;

    float ec0[8], es0[8], ec1[8], es1[8];
    {
        int t0 = 0, t1 = 0;
#pragma unroll
        for (int m = 1; m < 8; ++m) {
            t0 += kk0; if (t0 >= WIN) t0 -= WIN;
            ec0[m] = cTabF.c[t0]; es0[m] = cTabF.s[t0];
            t1 += kk1; if (t1 >= WIN) t1 -= WIN;
            ec1[m] = cTabF.c[t1]; es1[m] = cTabF.s[t1];
        }
    }
    double C40 = a0 ? cTabR.c4[kk0] : 0.0, S40 = a0 ? cTabR.s4[kk0] : 0.0;
    double C41 = a1 ? cTabR.c4[kk1] : 0.0, S41 = a1 ? cTabR.s4[kk1] : 0.0;
    const double C80 = cTabR.c8[kk0], S80 = cTabR.s8[kk0];
    const double C81 = cTabR.c8[kk1], S81 = cTabR.s8[kk1];

    double S0r, S0i, S1r, S1i;
    {   // ---- init: f64 Horner, descending 8-sample f32 groups ----
        float xa = Xs[440], xb = Xs[441];
        S0r = (double)fmaf(xb, ec0[1], xa);
        S0i = (double)(xb * es0[1]);
        S1r = (double)fmaf(xb, ec1[1], xa);
        S1i = (double)(xb * es1[1]);
        const float4* Xq = (const float4*)Xs;
#pragma unroll 1
        for (int t = 54; t >= 0; --t) {
            float4 va = Xq[2 * t], vb = Xq[2 * t + 1];
            float Dr0 = va.x;
            Dr0 = fmaf(va.y, ec0[1], Dr0); Dr0 = fmaf(va.z, ec0[2], Dr0);
            Dr0 = fmaf(va.w, ec0[3], Dr0); Dr0 = fmaf(vb.x, ec0[4], Dr0);
            Dr0 = fmaf(vb.y, ec0[5], Dr0); Dr0 = fmaf(vb.z, ec0[6], Dr0);
            Dr0 = fmaf(vb.w, ec0[7], Dr0);
            float Di0 = va.y * es0[1];
            Di0 = fmaf(va.z, es0[2], Di0); Di0 = fmaf(va.w, es0[3], Di0);
            Di0 = fmaf(vb.x, es0[4], Di0); Di0 = fmaf(vb.y, es0[5], Di0);
            Di0 = fmaf(vb.z, es0[6], Di0); Di0 = fmaf(vb.w, es0[7], Di0);
            double nr = fma(S0r, C80, fma(S0i, S80, (double)Dr0));
            double ni = fma(S0i, C80, fma(S0r, -S80, (double)Di0));
            S0r = nr; S0i = ni;
            float Dr1 = va.x;
            Dr1 = fmaf(va.y, ec1[1], Dr1); Dr1 = fmaf(va.z, ec1[2], Dr1);
            Dr1 = fmaf(va.w, ec1[3], Dr1); Dr1 = fmaf(vb.x, ec1[4], Dr1);
            Dr1 = fmaf(vb.y, ec1[5], Dr1); Dr1 = fmaf(vb.z, ec1[6], Dr1);
            Dr1 = fmaf(vb.w, ec1[7], Dr1);
            float Di1 = va.y * es1[1];
            Di1 = fmaf(va.z, es1[2], Di1); Di1 = fmaf(va.w, es1[3], Di1);
            Di1 = fmaf(vb.x, es1[4], Di1); Di1 = fmaf(vb.y, es1[5], Di1);
            Di1 = fmaf(vb.z, es1[6], Di1); Di1 = fmaf(vb.w, es1[7], Di1);
            nr = fma(S1r, C81, fma(S1i, S81, (double)Dr1));
            ni = fma(S1i, C81, fma(S1r, -S81, (double)Di1));
            S1r = nr; S1i = ni;
        }
    }
    if (!a0) { S0r = 0.0; S0i = 0.0; }
    if (!a1) { S1r = 0.0; S1i = 0.0; }

    const float4* Dq = (const float4*)Ds_;
    for (int b = 0; b < 16; ++b) {           // 16 batches x 8 windows
        unsigned long long key[8];
#pragma unroll
        for (int u = 0; u < 8; ++u) {
            if (b | u) {
                float4 d = Dq[b * 8 + u - 1];
                float Dr0 = fmaf(d.w, ec0[3], fmaf(d.z, ec0[2], fmaf(d.y, ec0[1], d.x)));
                float Di0 = fmaf(d.w, es0[3], fmaf(d.z, es0[2], d.y * es0[1]));
                double nr = S0r + (double)Dr0;
                double ni = S0i + (double)Di0;
                S0r = fma(nr, C40, -(ni * S40));
                S0i = fma(nr, S40, ni * C40);
                float Dr1 = fmaf(d.w, ec1[3], fmaf(d.z, ec1[2], fmaf(d.y, ec1[1], d.x)));
                float Di1 = fmaf(d.w, es1[3], fmaf(d.z, es1[2], d.y * es1[1]));
                nr = S1r + (double)Dr1;
                ni = S1i + (double)Di1;
                S1r = fma(nr, C41, -(ni * S41));
                S1i = fma(nr, S41, ni * C41);
            }
            float m0 = (float)(fabs(S0r) + fabs(S0i));
            float m1 = (float)(fabs(S1r) + fabs(S1i));
            unsigned long long key0 = ((unsigned long long)__float_as_uint(m0) << 32) | lo0;
            unsigned long long key1 = ((unsigned long long)__float_as_uint(m1) << 32) | lo1;
            key[u] = (key1 > key0) ? key1 : key0;
        }
        // ---- 8 interleaved u64 butterflies, stages 32,16,8,4 ----
#pragma unroll
        for (int s = 0; s < 4; ++s) {
            const int off = 32 >> s;
#pragma unroll
            for (int u = 0; u < 8; ++u) {
                unsigned long long o = shflx64(key[u], off);
                if (o > key[u]) key[u] = o;
            }
        }
        if (lane < 4) {
#pragma unroll
            for (int u = 0; u < 8; ++u) cand[b * 8 + u][wc * 4 + lane] = key[u];
        }
    }
    __syncthreads();
    // ---- merge 8 candidates per window; stash t-values in dead Ds_ region ----
    float* tfl = Ds_;
    if (tid < wlen) {
        unsigned long long best = cand[tid][0];
#pragma unroll
        for (int i = 1; i < 8; ++i) {
            unsigned long long c = cand[tid][i];
            if (c > best) best = c;
        }
        int a = 255 - (int)(best & 255u);
        a_arr[chunk * LC + tid] = a;
        tfl[tid] = 100.0f * (float)a;
    }
    __syncthreads();
    // ---- fused chunk map, ILP-2: bins tid and tid+128 chained interleaved ----
    {
        int b0 = tid, b1 = tid + 128;
        bool act1 = (b1 < NBINS);
        float mF0 = 100.0f * (float)b0;
        float mF1 = act1 ? 100.0f * (float)b1 : 100.0f;
        int rel0 = -1, rel1 = -1;
        for (int i = 0; i < wlen; ++i) {
            float t = tfl[i];
            if (fabsf(mF0 - t) > mF0 * 0.0594f) { mF0 = t; rel0 = i; }
            if (fabsf(mF1 - t) > mF1 * 0.0594f) { mF1 = t; rel1 = i; }
        }
        int bin0 = __float2int_rn(mF0 * 0.01f);
        M0[chunk * NBINS + b0] = (unsigned short)(((rel0 + 1) << 8) | bin0);
        if (act1) {
            int bin1 = __float2int_rn(mF1 * 0.01f);
            M0[chunk * NBINS + b1] = (unsigned short)(((rel1 + 1) << 8) | bin1);
        }
    }
}

// ---------------- Kernel D: compose GSZ consecutive chunk-maps -> M1 (int, abs rw) ----------------
__global__ __launch_bounds__(256) void k_sm1(const unsigned short* __restrict__ M0,
                                             int n_chunks, int* __restrict__ M1) {
    __shared__ unsigned short sm[GSZ * NBINS];   // 14.1 KB
    int g = blockIdx.x;
    int c0 = g * GSZ;
    int cn = min(GSZ, n_chunks - c0);
    for (int i = threadIdx.x; i < cn * NBINS; i += 256) sm[i] = M0[c0 * NBINS + i];
    __syncthreads();
    int b = threadIdx.x;
    if (b < NBINS) {
        int bin = b, rw = -1;
        for (int i = 0; i < cn; ++i) {
            unsigned short mp = sm[i * NBINS + bin];
            if (mp >> 8) { rw = (c0 + i) * LC + (int)(mp >> 8) - 1; bin = mp & 255; }
        }
        M1[g * NBINS + b] = ((rw + 1) << 8) | bin;
    }
}

// ---------------- Kernel E: per-chunk entries E0, all-LDS chains (dynamic LDS) ----------------
__global__ __launch_bounds__(256) void k_e0(const unsigned short* __restrict__ M0,
                                            const int* __restrict__ M1,
                                            int n_chunks, int ngrp,
                                            int* __restrict__ E0) {
    extern __shared__ char dyn[];
    int* m1s = (int*)dyn;                                  // ngrp*221 ints
    unsigned short* m0s = (unsigned short*)(m1s + ngrp * NBINS);  // GSZ*221 u16
    int g = blockIdx.x;
    int c0 = g * GSZ;
    int cn = min(GSZ, n_chunks - c0);
    for (int i = threadIdx.x; i < ngrp * NBINS; i += 256) m1s[i] = M1[i];
    for (int i = threadIdx.x; i < cn * NBINS; i += 256) m0s[i] = M0[c0 * NBINS + i];
    __syncthreads();
    int j = threadIdx.x;
    if (j < cn) {
        int bin = 0, rw = -1;
        for (int i = 0; i < g; ++i) {               // cross-group prefix through M1
            int mp = m1s[i * NBINS + bin];
            if (mp >> 8) { rw = (mp >> 8) - 1; bin = mp & 255; }
        }
        for (int q = 0; q < j; ++q) {               // within-group prefix through M0
            unsigned short mp = m0s[q * NBINS + bin];
            if (mp >> 8) { rw = (c0 + q) * LC + (int)(mp >> 8) - 1; bin = mp & 255; }
        }
        E0[c0 + j] = ((rw + 1) << 8) | bin;
    }
}

// ---------------- Kernel F: emit flags/freqs/durs + final (thread-per-window rescan) ----------------
__global__ __launch_bounds__(128) void k_emit(const int* __restrict__ a_arr,
    const int* __restrict__ E0, int n_win,
    float* __restrict__ flags, float* __restrict__ freqs, float* __restrict__ durs,
    float* __restrict__ out_final) {
    __shared__ float tf[LC];
    int j = blockIdx.x;
    int wbeg = j * LC;
    int cnt = n_win - wbeg; if (cnt > LC) cnt = LC;
    if (cnt <= 0) return;
    for (int i = threadIdx.x; i < cnt; i += 128) tf[i] = 100.0f * (float)a_arr[wbeg + i];
    __syncthreads();
    int t = threadIdx.x;
    if (t < cnt) {
        int st = E0[j];
        float maxF = 100.0f * (float)(st & 255);
        int rw = (st >> 8) - 1;
        float Ftime = (rw < 0) ? 0.0f : 4.0f * (float)rw;
        for (int i = 0; i < t; ++i) {
            float tv = tf[i];
            if (fabsf(maxF - tv) > maxF * 0.0594f) {
                maxF = tv; Ftime = 4.0f * (float)(wbeg + i);
            }
        }
        int w = wbeg + t;
        float tv = tf[t];
        float iw = 4.0f * (float)w;
        bool cond = fabsf(maxF - tv) > maxF * 0.0594f;
        flags[w] = cond ? 1.0f : 0.0f;
        freqs[w] = maxF;
        durs[w] = (iw - Ftime) * 1000.0f / 44100.0f;
        if (w == n_win - 1) {                    // fold final-state output here
            float fMax = cond ? tv : maxF;
            float fT   = cond ? iw : Ftime;
            out_final[0] = fMax;
            out_final[1] = (iw - fT) * 1000.0f / 44100.0f;
        }
    }
}

extern "C" void kernel_launch(void* const* d_in, const int* in_sizes, int n_in,
                              void* d_out, int out_size, void* d_ws, size_t ws_size,
                              hipStream_t stream) {
    const float* x = (const float*)d_in[0];
    int n = in_sizes[0];
    int n_win = (n - WIN + HOP - 1) / HOP;
    float* out = (float*)d_out;
    char* ws = (char*)d_ws;

    int n_chunks = (n_win + LC - 1) / LC;             // 1953 @ n=1e6
    int ngrp = (n_chunks + GSZ - 1) / GSZ;            // 62

    // ws layout (~1.93 MB)
    int* a_arr         = (int*)(ws + 0);                     // 1953*128*4 = 999,936 B
    unsigned short* M0 = (unsigned short*)(ws + 1000448);    // 1953*221*2 = 863,226 B
    int* M1            = (int*)(ws + 1864192);               // 62*221*4 = 54,808 B
    int* E0            = (int*)(ws + 1919232);               // 1953*4 = 7,812 B

    size_t e0_lds = (size_t)ngrp * NBINS * 4 + (size_t)GSZ * NBINS * 2;  // ~69 KB

    k_slide<<<dim3(n_chunks), dim3(128), 0, stream>>>(x, n, n_win, n_chunks, a_arr, M0);
    k_sm1<<<dim3(ngrp), dim3(256), 0, stream>>>(M0, n_chunks, M1);
    k_e0<<<dim3(ngrp), dim3(256), e0_lds, stream>>>(M0, M1, n_chunks, ngrp, E0);
    k_emit<<<dim3(n_chunks), dim3(128), 0, stream>>>(a_arr, E0, n_win,
                                                     out, out + (size_t)n_win,
                                                     out + 2 * (size_t)n_win,
                                                     out + 3 * (size_t)n_win);
}